// Round 5
// baseline (573.785 us; speedup 1.0000x reference)
//
#include <hip/hip_runtime.h>
#include <hip/hip_fp16.h>

// GCN: 3x GCNConv (34->4->4->2) + linear (2->4), N=500K nodes, E=8M edges.
// Round 5: fp16 gather tables. Round-4 aggs fetched 277MB/pass because the
// 8MB fp32 g-table couldn't stay resident in the 4MB per-XCD L2 (54% of the
// 8M random 64B-line gathers missed). half4 = 4MB (L1/2 ch: half2 = 2MB)
// fits L2 -> gathers become L2-hits. Accumulation stays fp32 in LDS.
// gcn(h)[d] = dinv[d]*(sum_{s->d} g[s] + g[d]) + b,  g[s] = dinv[s]*(h[s]@W).
//
// ws: bsize_pad | gcur_pad | bstart | dinv[N] f32 | ep[E] u32 | g1h[N] half4 |
//     g2h[N] half4   (g3h aliases g1h as half2)

#define MAXBUK 1024
#define BUCKET_BITS 9
#define BUCKET 512
#define PAD 16

#define BS_BLK 256
#define BS_CHUNK 8192

#define BIN_BLK 512
#define BIN_CHUNK 16384

#define AGG_BLK 512
#define SC_BLK 256

// --- kernel 1: bucket sizes (per-block LDS hist -> padded global merge) ---
__global__ void bsize_kernel(const int* __restrict__ dst, int* __restrict__ bsize,
                             int E, int nbuk) {
    __shared__ int hist[MAXBUK];
    int t = threadIdx.x;
    for (int b = t; b < nbuk; b += BS_BLK) hist[b] = 0;
    __syncthreads();
    int e0 = blockIdx.x * BS_CHUNK;
    int e1 = min(e0 + BS_CHUNK, E);
    int cn = e1 - e0;
    const int4* dv = (const int4*)(dst + e0);
    int n4 = cn >> 2;
    for (int i = t; i < n4; i += BS_BLK) {
        int4 d = dv[i];
        atomicAdd(&hist[d.x >> BUCKET_BITS], 1);
        atomicAdd(&hist[d.y >> BUCKET_BITS], 1);
        atomicAdd(&hist[d.z >> BUCKET_BITS], 1);
        atomicAdd(&hist[d.w >> BUCKET_BITS], 1);
    }
    for (int e = (n4 << 2) + t; e < cn; e += BS_BLK)
        atomicAdd(&hist[dst[e0 + e] >> BUCKET_BITS], 1);
    __syncthreads();
    for (int b = t; b < nbuk; b += BS_BLK)
        if (hist[b]) atomicAdd(&bsize[b * PAD], hist[b]);
}

// --- kernel 2: single-block exclusive scan over bucket sizes ---
__global__ void scan_kernel(const int* __restrict__ bsize, int* __restrict__ bstart,
                            int* __restrict__ gcur, int nbuk) {
    __shared__ int tmp[SC_BLK];
    __shared__ int carry;
    int t = threadIdx.x;
    if (t == 0) carry = 0;
    __syncthreads();
    for (int base = 0; base < nbuk; base += SC_BLK) {
        int i = base + t;
        int v = (i < nbuk) ? bsize[i * PAD] : 0;
        tmp[t] = v;
        __syncthreads();
        for (int off = 1; off < SC_BLK; off <<= 1) {
            int add = (t >= off) ? tmp[t - off] : 0;
            __syncthreads();
            tmp[t] += add;
            __syncthreads();
        }
        int excl = tmp[t] - v + carry;
        if (i < nbuk) { bstart[i] = excl; gcur[i * PAD] = excl; }
        __syncthreads();
        if (t == SC_BLK - 1) carry += tmp[t];
        __syncthreads();
    }
    if (t == 0) bstart[nbuk] = carry;
}

// --- kernel 3: LDS-staged binning; ep = (dst_local << 23) | src ---
__global__ void __launch_bounds__(BIN_BLK, 1)
bin_kernel(const int* __restrict__ src, const int* __restrict__ dst,
           int* __restrict__ gcur, unsigned* __restrict__ ep, int E, int nbuk) {
    __shared__ int hist[MAXBUK];
    __shared__ int lbase[MAXBUK + 1];
    __shared__ int gb[MAXBUK];
    __shared__ int stmp[BIN_BLK];
    __shared__ int scarry;
    __shared__ unsigned stage[BIN_CHUNK];
    int t = threadIdx.x;
    for (int b = t; b < nbuk; b += BIN_BLK) hist[b] = 0;
    if (t == 0) scarry = 0;
    __syncthreads();
    int e0 = blockIdx.x * BIN_CHUNK;
    int e1 = min(e0 + BIN_CHUNK, E);
    int cn = e1 - e0;
    const int4* dv = (const int4*)(dst + e0);
    const int4* sv = (const int4*)(src + e0);
    int n4 = cn >> 2;
    for (int i = t; i < n4; i += BIN_BLK) {
        int4 d = dv[i];
        atomicAdd(&hist[d.x >> BUCKET_BITS], 1);
        atomicAdd(&hist[d.y >> BUCKET_BITS], 1);
        atomicAdd(&hist[d.z >> BUCKET_BITS], 1);
        atomicAdd(&hist[d.w >> BUCKET_BITS], 1);
    }
    for (int e = (n4 << 2) + t; e < cn; e += BIN_BLK)
        atomicAdd(&hist[dst[e0 + e] >> BUCKET_BITS], 1);
    __syncthreads();
    for (int base = 0; base < nbuk; base += BIN_BLK) {
        int i = base + t;
        int v = (i < nbuk) ? hist[i] : 0;
        stmp[t] = v;
        __syncthreads();
        for (int off = 1; off < BIN_BLK; off <<= 1) {
            int add = (t >= off) ? stmp[t - off] : 0;
            __syncthreads();
            stmp[t] += add;
            __syncthreads();
        }
        if (i < nbuk) lbase[i] = stmp[t] - v + scarry;
        __syncthreads();
        if (t == BIN_BLK - 1) scarry += stmp[t];
        __syncthreads();
    }
    if (t == 0) lbase[nbuk] = scarry;
    for (int b = t; b < nbuk; b += BIN_BLK) {
        int c = hist[b];
        gb[b] = c ? atomicAdd(&gcur[b * PAD], c) : 0;
        hist[b] = 0;
    }
    __syncthreads();
    for (int i = t; i < n4; i += BIN_BLK) {
        int4 d = dv[i];
        int4 s = sv[i];
        int bk, r;
        bk = d.x >> BUCKET_BITS; r = atomicAdd(&hist[bk], 1);
        stage[lbase[bk] + r] = ((unsigned)(d.x & (BUCKET - 1)) << 23) | (unsigned)s.x;
        bk = d.y >> BUCKET_BITS; r = atomicAdd(&hist[bk], 1);
        stage[lbase[bk] + r] = ((unsigned)(d.y & (BUCKET - 1)) << 23) | (unsigned)s.y;
        bk = d.z >> BUCKET_BITS; r = atomicAdd(&hist[bk], 1);
        stage[lbase[bk] + r] = ((unsigned)(d.z & (BUCKET - 1)) << 23) | (unsigned)s.z;
        bk = d.w >> BUCKET_BITS; r = atomicAdd(&hist[bk], 1);
        stage[lbase[bk] + r] = ((unsigned)(d.w & (BUCKET - 1)) << 23) | (unsigned)s.w;
    }
    for (int e = (n4 << 2) + t; e < cn; e += BIN_BLK) {
        int d = dst[e0 + e];
        int bk = d >> BUCKET_BITS;
        int r = atomicAdd(&hist[bk], 1);
        stage[lbase[bk] + r] = ((unsigned)(d & (BUCKET - 1)) << 23) | (unsigned)src[e0 + e];
    }
    __syncthreads();
    int wid = t >> 6, lane = t & 63;
    for (int b = wid; b < nbuk; b += (BIN_BLK >> 6)) {
        int lo = lbase[b];
        int c = lbase[b + 1] - lo;
        unsigned* dp = ep + gb[b];
        for (int j = lane; j < c; j += 64) dp[j] = stage[lo + j];
    }
}

// --- kernel 4: fused per-bucket degree->dinv + layer-1 transform -> half4 ---
__global__ void dtf1_kernel(const unsigned* __restrict__ ep, const int* __restrict__ bstart,
                            const float* __restrict__ x, const float* __restrict__ W1,
                            float* __restrict__ dinv, uint2* __restrict__ g1h, int N) {
    __shared__ int cnt[BUCKET];
    __shared__ float sW[136];
    int t = threadIdx.x, b = blockIdx.x;
    if (t < 136) sW[t] = W1[t];
    if (t < BUCKET) cnt[t] = 0;
    __syncthreads();
    int s = bstart[b], e = bstart[b + 1];
    for (int p = s + t; p < e; p += AGG_BLK)
        atomicAdd(&cnt[ep[p] >> 23], 1);
    __syncthreads();
    int gbase = b << BUCKET_BITS;
    int i = gbase + t;
    if (t < BUCKET && i < N) {
        float dv = rsqrtf((float)cnt[t] + 1.0f);
        dinv[i] = dv;
        const float2* xr = (const float2*)(x + (size_t)i * 34);
        float o0 = 0.f, o1 = 0.f, o2 = 0.f, o3 = 0.f;
#pragma unroll
        for (int k = 0; k < 17; ++k) {
            float2 v = xr[k];
            o0 = fmaf(v.x, sW[(2 * k) * 4 + 0], o0);
            o1 = fmaf(v.x, sW[(2 * k) * 4 + 1], o1);
            o2 = fmaf(v.x, sW[(2 * k) * 4 + 2], o2);
            o3 = fmaf(v.x, sW[(2 * k) * 4 + 3], o3);
            o0 = fmaf(v.y, sW[(2 * k + 1) * 4 + 0], o0);
            o1 = fmaf(v.y, sW[(2 * k + 1) * 4 + 1], o1);
            o2 = fmaf(v.y, sW[(2 * k + 1) * 4 + 2], o2);
            o3 = fmaf(v.y, sW[(2 * k + 1) * 4 + 3], o3);
        }
        __half2 lo = __floats2half2_rn(o0 * dv, o1 * dv);
        __half2 hi = __floats2half2_rn(o2 * dv, o3 * dv);
        uint2 pk;
        pk.x = *(unsigned*)&lo;
        pk.y = *(unsigned*)&hi;
        g1h[i] = pk;
    }
}

__device__ __forceinline__ void acc_edge4(unsigned pe, const uint2* __restrict__ g,
                                          float (*acc)[BUCKET]) {
    uint2 pk = g[pe & 0x7FFFFFu];
    __half2 lo = *(__half2*)&pk.x;
    __half2 hi = *(__half2*)&pk.y;
    float2 a = __half22float2(lo);
    float2 c = __half22float2(hi);
    int l = pe >> 23;
    atomicAdd(&acc[0][l], a.x);
    atomicAdd(&acc[1][l], a.y);
    atomicAdd(&acc[2][l], c.x);
    atomicAdd(&acc[3][l], c.y);
}

// --- kernel 5: agg over g1h + finish layer1 + W2 -> g2h (half4) ---
__global__ void agg12_kernel(const unsigned* __restrict__ ep, const int* __restrict__ bstart,
                             const uint2* __restrict__ g1h, const float* __restrict__ dinv,
                             const float* __restrict__ b1, const float* __restrict__ W2,
                             uint2* __restrict__ g2h, int N) {
    __shared__ float acc[4][BUCKET];
    int t = threadIdx.x, b = blockIdx.x;
    int gbase = b << BUCKET_BITS;
    int nn = min(BUCKET, N - gbase);
    if (t < nn) {
        uint2 pk = g1h[gbase + t];  // self loop
        __half2 lo = *(__half2*)&pk.x;
        __half2 hi = *(__half2*)&pk.y;
        float2 a = __half22float2(lo);
        float2 c = __half22float2(hi);
        acc[0][t] = a.x; acc[1][t] = a.y; acc[2][t] = c.x; acc[3][t] = c.y;
    }
    __syncthreads();
    int s = bstart[b], e = bstart[b + 1];
    int p = s + 2 * t;
    for (; p + 1 < e; p += 2 * AGG_BLK) {
        unsigned pe0 = ep[p], pe1 = ep[p + 1];
        acc_edge4(pe0, g1h, acc);
        acc_edge4(pe1, g1h, acc);
    }
    if (p < e) acc_edge4(ep[p], g1h, acc);
    __syncthreads();
    if (t < nn) {
        float dv = dinv[gbase + t];
        float h0 = fmaxf(fmaf(acc[0][t], dv, b1[0]), 0.f);
        float h1 = fmaxf(fmaf(acc[1][t], dv, b1[1]), 0.f);
        float h2 = fmaxf(fmaf(acc[2][t], dv, b1[2]), 0.f);
        float h3 = fmaxf(fmaf(acc[3][t], dv, b1[3]), 0.f);
        float o0 = dv * (h0 * W2[0] + h1 * W2[4] + h2 * W2[8] + h3 * W2[12]);
        float o1 = dv * (h0 * W2[1] + h1 * W2[5] + h2 * W2[9] + h3 * W2[13]);
        float o2 = dv * (h0 * W2[2] + h1 * W2[6] + h2 * W2[10] + h3 * W2[14]);
        float o3 = dv * (h0 * W2[3] + h1 * W2[7] + h2 * W2[11] + h3 * W2[15]);
        __half2 lo = __floats2half2_rn(o0, o1);
        __half2 hi = __floats2half2_rn(o2, o3);
        uint2 pk;
        pk.x = *(unsigned*)&lo;
        pk.y = *(unsigned*)&hi;
        g2h[gbase + t] = pk;
    }
}

// --- kernel 6: agg over g2h + finish layer2 + W3 -> g3h (half2) ---
__global__ void agg23_kernel(const unsigned* __restrict__ ep, const int* __restrict__ bstart,
                             const uint2* __restrict__ g2h, const float* __restrict__ dinv,
                             const float* __restrict__ b2, const float* __restrict__ W3,
                             unsigned* __restrict__ g3h, int N) {
    __shared__ float acc[4][BUCKET];
    int t = threadIdx.x, b = blockIdx.x;
    int gbase = b << BUCKET_BITS;
    int nn = min(BUCKET, N - gbase);
    if (t < nn) {
        uint2 pk = g2h[gbase + t];
        __half2 lo = *(__half2*)&pk.x;
        __half2 hi = *(__half2*)&pk.y;
        float2 a = __half22float2(lo);
        float2 c = __half22float2(hi);
        acc[0][t] = a.x; acc[1][t] = a.y; acc[2][t] = c.x; acc[3][t] = c.y;
    }
    __syncthreads();
    int s = bstart[b], e = bstart[b + 1];
    int p = s + 2 * t;
    for (; p + 1 < e; p += 2 * AGG_BLK) {
        unsigned pe0 = ep[p], pe1 = ep[p + 1];
        acc_edge4(pe0, g2h, acc);
        acc_edge4(pe1, g2h, acc);
    }
    if (p < e) acc_edge4(ep[p], g2h, acc);
    __syncthreads();
    if (t < nn) {
        float dv = dinv[gbase + t];
        float h0 = fmaxf(fmaf(acc[0][t], dv, b2[0]), 0.f);
        float h1 = fmaxf(fmaf(acc[1][t], dv, b2[1]), 0.f);
        float h2 = fmaxf(fmaf(acc[2][t], dv, b2[2]), 0.f);
        float h3 = fmaxf(fmaf(acc[3][t], dv, b2[3]), 0.f);
        float o0 = dv * (h0 * W3[0] + h1 * W3[2] + h2 * W3[4] + h3 * W3[6]);
        float o1 = dv * (h0 * W3[1] + h1 * W3[3] + h2 * W3[5] + h3 * W3[7]);
        __half2 o = __floats2half2_rn(o0, o1);
        g3h[gbase + t] = *(unsigned*)&o;
    }
}

// --- kernel 7: agg over g3h (half2) + finish layer3 + linear -> out ---
__global__ void agg3f_kernel(const unsigned* __restrict__ ep, const int* __restrict__ bstart,
                             const unsigned* __restrict__ g3h, const float* __restrict__ dinv,
                             const float* __restrict__ b3, const float* __restrict__ Wl,
                             const float* __restrict__ bl, float* __restrict__ out, int N) {
    __shared__ float acc[2][BUCKET];
    int t = threadIdx.x, b = blockIdx.x;
    int gbase = b << BUCKET_BITS;
    int nn = min(BUCKET, N - gbase);
    if (t < nn) {
        unsigned pk = g3h[gbase + t];
        float2 v = __half22float2(*(__half2*)&pk);
        acc[0][t] = v.x; acc[1][t] = v.y;
    }
    __syncthreads();
    int s = bstart[b], e = bstart[b + 1];
    int p = s + 2 * t;
    for (; p + 1 < e; p += 2 * AGG_BLK) {
        unsigned pe0 = ep[p], pe1 = ep[p + 1];
        unsigned q0 = g3h[pe0 & 0x7FFFFFu];
        unsigned q1 = g3h[pe1 & 0x7FFFFFu];
        float2 v0 = __half22float2(*(__half2*)&q0);
        float2 v1 = __half22float2(*(__half2*)&q1);
        int l0 = pe0 >> 23, l1 = pe1 >> 23;
        atomicAdd(&acc[0][l0], v0.x);
        atomicAdd(&acc[1][l0], v0.y);
        atomicAdd(&acc[0][l1], v1.x);
        atomicAdd(&acc[1][l1], v1.y);
    }
    if (p < e) {
        unsigned pe = ep[p];
        unsigned q = g3h[pe & 0x7FFFFFu];
        float2 v = __half22float2(*(__half2*)&q);
        int l = pe >> 23;
        atomicAdd(&acc[0][l], v.x);
        atomicAdd(&acc[1][l], v.y);
    }
    __syncthreads();
    if (t < nn) {
        float dv = dinv[gbase + t];
        float h0 = fmaxf(fmaf(acc[0][t], dv, b3[0]), 0.f);
        float h1 = fmaxf(fmaf(acc[1][t], dv, b3[1]), 0.f);
        float4 o;
        o.x = fmaf(h0, Wl[0], fmaf(h1, Wl[4], bl[0]));
        o.y = fmaf(h0, Wl[1], fmaf(h1, Wl[5], bl[1]));
        o.z = fmaf(h0, Wl[2], fmaf(h1, Wl[6], bl[2]));
        o.w = fmaf(h0, Wl[3], fmaf(h1, Wl[7], bl[3]));
        ((float4*)out)[gbase + t] = o;
        ((float2*)(out + (size_t)4 * N))[gbase + t] = make_float2(h0, h1);
    }
}

extern "C" void kernel_launch(void* const* d_in, const int* in_sizes, int n_in,
                              void* d_out, int out_size, void* d_ws, size_t ws_size,
                              hipStream_t stream) {
    const float* x  = (const float*)d_in[0];
    const int*   ei = (const int*)d_in[1];
    const float* W1 = (const float*)d_in[2];
    const float* b1 = (const float*)d_in[3];
    const float* W2 = (const float*)d_in[4];
    const float* b2 = (const float*)d_in[5];
    const float* W3 = (const float*)d_in[6];
    const float* b3 = (const float*)d_in[7];
    const float* Wl = (const float*)d_in[8];
    const float* bl = (const float*)d_in[9];
    float* out = (float*)d_out;

    const int N = in_sizes[0] / 34;
    const int E = in_sizes[1] / 2;
    const int* src = ei;
    const int* dst = ei + E;
    const int NBUK = (N + BUCKET - 1) >> BUCKET_BITS;

    auto al16 = [](size_t v) { return (v + 15) & ~(size_t)15; };
    char* w = (char*)d_ws;
    size_t off = 0;
    int*      bsize  = (int*)(w + off);      off += al16((size_t)NBUK * PAD * 4);
    int*      gcur   = (int*)(w + off);      off += al16((size_t)NBUK * PAD * 4);
    int*      bstart = (int*)(w + off);      off += al16((size_t)(NBUK + 1) * 4);
    float*    dinv   = (float*)(w + off);    off += al16((size_t)N * 4);
    unsigned* ep     = (unsigned*)(w + off); off += al16((size_t)E * 4);
    uint2*    g1h    = (uint2*)(w + off);    off += al16((size_t)N * 8);
    uint2*    g2h    = (uint2*)(w + off);
    unsigned* g3h    = (unsigned*)g1h;  // g1 dead once g3 is written

    const int nb_bs  = (E + BS_CHUNK - 1) / BS_CHUNK;
    const int nb_bin = (E + BIN_CHUNK - 1) / BIN_CHUNK;

    hipMemsetAsync(bsize, 0, (size_t)NBUK * PAD * 4, stream);
    bsize_kernel<<<nb_bs, BS_BLK, 0, stream>>>(dst, bsize, E, NBUK);
    scan_kernel<<<1, SC_BLK, 0, stream>>>(bsize, bstart, gcur, NBUK);
    bin_kernel<<<nb_bin, BIN_BLK, 0, stream>>>(src, dst, gcur, ep, E, NBUK);
    dtf1_kernel<<<NBUK, AGG_BLK, 0, stream>>>(ep, bstart, x, W1, dinv, g1h, N);
    agg12_kernel<<<NBUK, AGG_BLK, 0, stream>>>(ep, bstart, g1h, dinv, b1, W2, g2h, N);
    agg23_kernel<<<NBUK, AGG_BLK, 0, stream>>>(ep, bstart, g2h, dinv, b2, W3, g3h, N);
    agg3f_kernel<<<NBUK, AGG_BLK, 0, stream>>>(ep, bstart, g3h, dinv, b3, Wl, bl, out, N);
}